// Round 3
// baseline (107.747 us; speedup 1.0000x reference)
//
#include <hip/hip_runtime.h>
#include <cstdint>

#pragma clang fp contract(off)

#define NB      32
#define NC      18
#define NA      8400
#define NCH     (4 + NC)
#define NTASK   (NB * NC)      // 576
#define TOPK    300
#define TARGET  316        // TOPK + margin: absorbs sigmoid-tie rank ambiguity
#define NBINS   2048
#define CAP     1024
#define CONF    0.25f
#define IOU_T   0.45f
#define NT      512
#define NW      (NT / 64)
// Prefilter: N(0,1) logits, top-316 cutoff ~1.75 +- 0.1; count(x>1.4) in [553,803] (5-sigma).
// Fast path requires TARGET <= s_cnt <= CAP, else exact fallback.
#define PREF_X  1.4f
// sigmoid(x) > 0.25  <=>  x > -ln(3). Outside [XLO,XHI] analytic compare is exact.
#define XHI     (-1.0984f)
#define XLO     (-1.0988f)

// Fast-path binning: keys (mono_key of x>1.4) start at 0xBFB33333.
#define FAST_KBASE 0xBFB00000u
#define FAST_SHIFT 14
// Fallback binning: conf_pass keys start ~0x40735C26.
#define FB_KBASE   0x40000000u
#define FB_SHIFT   21

// Exact div-free IoU compare: RN_f32(inter/D) > 0.45f  <=>  inter > M45*D.
// M45 = fp32(0.45) + 2^-26 (25-bit mantissa, exact in f64; x 24-bit D -> exact
// 49-bit product). Tie rounds-to-even back to 0.45f => not >, matching. Bit-exact.
#define M45 (30198989.0 / 67108864.0)

typedef unsigned long long ull;

__device__ __forceinline__ float sigmoidf(float x) {
    return 1.0f / (1.0f + expf(-x));
}
__device__ __forceinline__ unsigned int mono_key(unsigned int bits) {
    return (bits & 0x80000000u) ? ~bits : (bits | 0x80000000u);
}
__device__ __forceinline__ unsigned int mono_inv(unsigned int key) {
    return (key & 0x80000000u) ? (key ^ 0x80000000u) : ~key;
}
__device__ __forceinline__ bool conf_pass(float x) {
    if (x >= XHI) return true;
    if (x <= XLO) return false;
    return sigmoidf(x) > CONF;   // rare exact band (~1 element per task)
}
__device__ __forceinline__ unsigned int make_key(float x) {
    return conf_pass(x) ? mono_key(__float_as_uint(x)) : 0u;
}
__device__ __forceinline__ ull readlane64(ull v, int i) {
    unsigned lo = (unsigned)__builtin_amdgcn_readlane((int)(unsigned)(v & 0xFFFFFFFFull), i);
    unsigned hi = (unsigned)__builtin_amdgcn_readlane((int)(unsigned)(v >> 32), i);
    return ((ull)hi << 32) | (ull)lo;
}
__device__ __forceinline__ ull shflxor64(ull v, int m) {
    unsigned lo = (unsigned)__shfl_xor((int)(unsigned)(v & 0xFFFFFFFFull), m, 64);
    unsigned hi = (unsigned)__shfl_xor((int)(unsigned)(v >> 32), m, 64);
    return ((ull)hi << 32) | (ull)lo;
}

// Suffix-find over hist: T1 s.t. count(bins > T1) < target <= count(bins >= T1).
__device__ __forceinline__ void suffix_find(unsigned int* hist, unsigned int* wtot,
                                            int target, int tid, int* s_T1) {
    const int base = tid * (NBINS / NT);
    unsigned int v = 0;
#pragma unroll
    for (int k = 0; k < NBINS / NT; ++k) v += hist[base + k];
    const int lane = tid & 63;
    unsigned int s = v;
#pragma unroll
    for (int d = 1; d < 64; d <<= 1) {
        unsigned int o = __shfl_down(s, d, 64);
        if (lane + d < 64) s += o;
    }
    if (lane == 0) wtot[tid >> 6] = s;
    __syncthreads();
    unsigned int above_waves = 0;
    for (int wv = (tid >> 6) + 1; wv < NW; ++wv) above_waves += wtot[wv];
    unsigned int acc = (s - v) + above_waves;
    for (int bin = base + (NBINS / NT) - 1; bin >= base; --bin) {
        unsigned int cnt = hist[bin];
        if (acc < (unsigned int)target && acc + cnt >= (unsigned int)target) *s_T1 = bin;
        acc += cnt;
    }
    __syncthreads();
}

// Pool layout: [0,8192) hist -> cand2 -> sSort -> sSup(12000B, spills into cand
// region) ; [8192,16384) cand. All reuses are barrier-separated.
#define OFF_CAND   8192
#define POOL1_BYTES 16384

// PIN: keep loaded mask words in VGPRs across the serial scan (compiler
// otherwise rematerializes the loads inside the scan loop).
#define PIN64(x) asm volatile("" : "+v"(x))

// ============ Fused: select -> sort -> mask -> greedy scan -> output.
// One block per task; all intermediates in LDS.
// Data facts exploited: (1) only ~25% of boxes have w>0 && h>0; area_i==0.0f
// => inter(i,j)==0.0f exactly (RN monotone) => zero mask rows, skipped in mask
// build AND greedy scan. (2) Ranking of the ~320 selected keys is done by a
// 512-wide bitonic sort (keys unique via ~idx low word; pad 0 sorts last) --
// identical comparator (ull >) => identical ranking as rank-by-counting, at
// O(F log^2 F) instead of O(F^2) LDS-broadcast traffic. ============
__global__ __launch_bounds__(NT, 4) void k_fused(const float* __restrict__ in,
                                                 float* __restrict__ out) {
    __shared__ __align__(16) unsigned char pool[POOL1_BYTES];
    __shared__ __align__(16) float4 sBox[TOPK];
    __shared__ float sVal[TOPK];
    __shared__ float sAr[TOPK];
    __shared__ unsigned int wtot[NW];
    __shared__ unsigned int s_cnt, s_cnt2;
    __shared__ int s_T1;

    unsigned int* hist = (unsigned int*)pool;
    ull* cand2 = (ull*)pool;
    ull* cand  = (ull*)(pool + OFF_CAND);
    ull* sSort = (ull*)pool;              // valid after cand2 reads done
    ull* sSup  = (ull*)pool;              // valid after sort/rank barrier

    const int tid = threadIdx.x;
    const int lane = tid & 63;
    const int wave = tid >> 6;
    const ull ltm = (1ull << lane) - 1ull;
    const int t = blockIdx.x;
    // XCD swizzle: image b -> XCD b%8
    const int b = (t & 7) + 8 * ((t >> 3) & 3);
    const int c = t >> 5;
    const float* cls = in + (size_t)b * NCH * NA + (size_t)(4 + c) * NA;
    const float* box = in + (size_t)b * NCH * NA;

    for (int i = tid; i < NBINS; i += NT) hist[i] = 0;
    // zero rows that select may leave unwritten (rank >= numSel)
    for (int r = tid; r < TOPK; r += NT) {
        sBox[r] = float4{0.f, 0.f, 0.f, 0.f};
        sVal[r] = 0.f;
        sAr[r] = 0.f;
    }
    if (tid == 0) { s_cnt = 0; s_cnt2 = 0; s_T1 = -1; }
    __syncthreads();

    // P1: prefilter x>1.4, wave-aggregated compaction, fused refine histogram.
    // 2-deep software prefetch hides most of the global-load latency.
    {
        const float4* cls4 = (const float4*)cls;
        int q = tid;                       // tid < NT <= NA/4: first load valid
        float4 v = cls4[q];
        while (true) {
            const int qn = q + NT;
            const bool more = qn < NA / 4;
            float4 vn;
            if (more) vn = cls4[qn];

            const unsigned int i0 = (unsigned int)q * 4u;
            float xs[4] = {v.x, v.y, v.z, v.w};
            ull m[4];
            unsigned int cnt = 0;
#pragma unroll
            for (int u = 0; u < 4; ++u) {
                m[u] = __ballot(xs[u] > PREF_X);
                cnt += (unsigned int)__popcll(m[u]);
            }
            if (cnt) {
                unsigned int base = 0;
                if (lane == 0) base = atomicAdd(&s_cnt, cnt);
                base = (unsigned int)__builtin_amdgcn_readfirstlane((int)base);
                unsigned int pre = 0;
#pragma unroll
                for (int u = 0; u < 4; ++u) {
                    if (xs[u] > PREF_X) {
                        unsigned int mk = mono_key(__float_as_uint(xs[u]));
                        atomicAdd(&hist[min((mk - FAST_KBASE) >> FAST_SHIFT,
                                            (unsigned)(NBINS - 1))], 1u);
                        unsigned int p = base + pre + (unsigned int)__popcll(m[u] & ltm);
                        if (p < CAP)
                            cand[p] = ((ull)mk << 32) | (ull)(~(i0 + u));
                    }
                    pre += (unsigned int)__popcll(m[u]);
                }
            }
            if (!more) break;
            v = vn; q = qn;
        }
    }
    __syncthreads();

    const int pcnt = (int)s_cnt;
    if (pcnt >= TARGET && pcnt <= CAP) {
        // ---- fast path ----
        suffix_find(hist, wtot, TARGET, tid, &s_T1);
        const ull thr = ((ull)FAST_KBASE + ((ull)(unsigned int)s_T1 << FAST_SHIFT)) << 32;
        const int iters = (pcnt + NT - 1) / NT;
        for (int it = 0; it < iters; ++it) {
            int e = tid + it * NT;
            bool act = e < pcnt;
            ull k = act ? cand[e] : 0ull;
            bool sel = act && (k >= thr);
            ull mb = __ballot(sel);
            unsigned int cnt = (unsigned int)__popcll(mb);
            if (cnt) {
                unsigned int basep = 0;
                if (lane == 0) basep = atomicAdd(&s_cnt2, cnt);
                basep = (unsigned int)__builtin_amdgcn_readfirstlane((int)basep);
                if (sel) {
                    float xv = __uint_as_float(mono_inv((unsigned int)(k >> 32)));
                    float sv = sigmoidf(xv);
                    unsigned int p = basep + (unsigned int)__popcll(mb & ltm);
                    if (p < CAP)
                        cand2[p] = ((ull)__float_as_uint(sv) << 32) | (k & 0xFFFFFFFFull);
                }
            }
        }
        __syncthreads();
    } else {
        // ---- exact fallback (rare): re-zero hist, full conf_pass histogram ----
        __syncthreads();
        for (int i = tid; i < NBINS; i += NT) hist[i] = 0;
        __syncthreads();
        {
            const float4* cls4 = (const float4*)cls;
            for (int q = tid; q < NA / 4; q += NT) {
                float4 v = cls4[q];
                unsigned int kx = make_key(v.x), ky = make_key(v.y);
                unsigned int kz = make_key(v.z), kw = make_key(v.w);
                if (kx) atomicAdd(&hist[min((kx - FB_KBASE) >> FB_SHIFT, (unsigned)(NBINS - 1))], 1u);
                if (ky) atomicAdd(&hist[min((ky - FB_KBASE) >> FB_SHIFT, (unsigned)(NBINS - 1))], 1u);
                if (kz) atomicAdd(&hist[min((kz - FB_KBASE) >> FB_SHIFT, (unsigned)(NBINS - 1))], 1u);
                if (kw) atomicAdd(&hist[min((kw - FB_KBASE) >> FB_SHIFT, (unsigned)(NBINS - 1))], 1u);
            }
        }
        __syncthreads();
        suffix_find(hist, wtot, TARGET, tid, &s_T1);
        {
            const ull thr = (s_T1 < 0) ? 0ull
                : ((ull)FB_KBASE + ((ull)(unsigned int)s_T1 << FB_SHIFT));
            const float4* cls4 = (const float4*)cls;
            for (int q = tid; q < NA / 4; q += NT) {
                float4 v = cls4[q];
                const unsigned int i0 = (unsigned int)q * 4u;
                float xs[4] = {v.x, v.y, v.z, v.w};
#pragma unroll
                for (int u = 0; u < 4; ++u) {
                    unsigned int d = make_key(xs[u]);
                    if (d && (ull)d >= thr) {
                        unsigned int p = atomicAdd(&s_cnt2, 1u);
                        if (p < CAP) {
                            float sv = sigmoidf(xs[u]);
                            cand2[p] = ((ull)__float_as_uint(sv) << 32) | (ull)(~(i0 + u));
                        }
                    }
                }
            }
        }
        __syncthreads();
    }

    const int F = min((int)s_cnt2, CAP);
    const int numSel = min(F, TOPK);

    if (F <= NT) {
        // ---- bitonic-512 descending sort; thread tid ends holding rank-tid key.
        // Keys unique (low word = ~idx); pad 0 sorts last (real keys have
        // positive high word). Comparator identical to rank-by-counting (ull >)
        // -> identical ranking, bit-exact downstream. ----
        ull sk = (tid < F) ? cand2[tid] : 0ull;
        __syncthreads();              // all cand2 reads done; pool -> sSort
        for (int k2 = 2; k2 <= NT; k2 <<= 1) {
            for (int j = k2 >> 1; j > 0; j >>= 1) {
                ull other;
                if (j >= 64) {
                    sSort[tid] = sk;
                    __syncthreads();
                    other = sSort[tid ^ j];
                    __syncthreads();
                } else {
                    other = shflxor64(sk, j);
                }
                const bool takeMax = (((tid & j) == 0) == ((tid & k2) == 0));
                if (takeMax ? (other > sk) : (other < sk)) sk = other;
            }
        }
        // gather box for rank tid (fp expressions identical to before -> bit-exact)
        if (tid < numSel) {
            unsigned int i = ~(unsigned int)(sk & 0xFFFFFFFFull);
            float cx = box[i];
            float cy = box[NA + i];
            float w  = box[2 * NA + i];
            float h  = box[3 * NA + i];
            float hw = w * 0.5f, hh = h * 0.5f;
            float x1 = cx - hw, y1 = cy - hh, x2 = cx + hw, y2 = cy + hh;
            sBox[tid] = float4{x1, y1, x2, y2};
            sVal[tid] = __uint_as_float((unsigned int)(sk >> 32));
            sAr[tid] = fmaxf(x2 - x1, 0.f) * fmaxf(y2 - y1, 0.f);
        }
        __syncthreads();              // sSort dead; pool -> sSup
    } else {
        // ---- rare F > 512: original O(F^2) rank-by-counting path ----
        for (int e = tid; e < F; e += NT) {
            ull k = cand2[e];
            int rank = 0;
            int o = 0;
#pragma unroll 2
            for (; o + 4 <= F; o += 4) {
                ulonglong2 p0 = *(const ulonglong2*)&cand2[o];
                ulonglong2 p1 = *(const ulonglong2*)&cand2[o + 2];
                rank += (p0.x > k) + (p0.y > k) + (p1.x > k) + (p1.y > k);
            }
            for (; o < F; ++o) rank += (cand2[o] > k) ? 1 : 0;
            if (rank < TOPK) {
                unsigned int i = ~(unsigned int)(k & 0xFFFFFFFFull);
                float cx = box[i];
                float cy = box[NA + i];
                float w  = box[2 * NA + i];
                float h  = box[3 * NA + i];
                float hw = w * 0.5f, hh = h * 0.5f;
                float x1 = cx - hw, y1 = cy - hh, x2 = cx + hw, y2 = cy + hh;
                sBox[rank] = float4{x1, y1, x2, y2};
                sVal[rank] = __uint_as_float((unsigned int)(k >> 32));
                sAr[rank] = fmaxf(x2 - x1, 0.f) * fmaxf(y2 - y1, 0.f);
            }
        }
        __syncthreads();              // cand2 dead; pool -> sSup
    }

    // ---- suppression-mask build: rows striped across the 8 waves.
    // Zero-area rows (~75%) provably produce all-zero words -> skip their IoU
    // (and their sBox broadcast load) entirely. ----
    float4 cb[5];
    float ca[5];
#pragma unroll
    for (int w = 0; w < 5; ++w) {
        int j = (w << 6) + lane;
        bool v = j < TOPK;
        cb[w] = v ? sBox[j] : float4{0.f, 0.f, 0.f, 0.f};
        ca[w] = v ? sAr[j] : 0.f;
    }
    for (int r = wave; r < TOPK; r += NW) {
        float ai = sAr[r];
        const bool act = (r < numSel) && (ai > 0.0f);   // wave-uniform row skip
        float4 bi = float4{0.f, 0.f, 0.f, 0.f};
        if (act) bi = sBox[r];
        const int w0 = r >> 6;             // words < w0 have all columns <= r
#pragma unroll
        for (int w = 0; w < 5; ++w) {
            ull bal = 0ull;
            if (w >= w0 && act) {          // uniform branch
                const int j = (w << 6) + lane;
                bool supb = false;
                if (j < numSel && j > r) {
                    float xx1 = fmaxf(bi.x, cb[w].x);
                    float yy1 = fmaxf(bi.y, cb[w].y);
                    float xx2 = fminf(bi.z, cb[w].z);
                    float yy2 = fminf(bi.w, cb[w].w);
                    float iw = fmaxf(xx2 - xx1, 0.0f);
                    float ih = fmaxf(yy2 - yy1, 0.0f);
                    float inter = iw * ih;
                    float un = ai + ca[w] - inter;
                    float D = fmaxf(un, 1e-9f);
                    supb = (double)inter > M45 * (double)D;  // == RN(inter/D) > 0.45f
                }
                bal = __ballot(supb);
            }
            if (lane == 0) sSup[r * 5 + w] = bal;
        }
    }
    __syncthreads();

    // ---- greedy scan (wave 0 only). Zero-skip: rows whose 5 mask words are
    // all zero contribute nothing to rem regardless of kept-status -> iterate
    // only set bits of nz (ballot of nonzero rows), in increasing row order. ----
    if (wave != 0) return;

    ull rem0 = 0, rem1 = 0, rem2 = 0, rem3 = 0, rem4 = 0;
    {
        const ull* p = sSup + (size_t)lane * 5;
        ull B0 = p[0], B1 = p[1], B2 = p[2], B3 = p[3], B4 = p[4];
        PIN64(B0); PIN64(B1); PIN64(B2); PIN64(B3); PIN64(B4);
        ull nz = __ballot((B0 | B1 | B2 | B3 | B4) != 0ull);
        while (nz) {
            int i = __builtin_ctzll(nz);
            nz &= nz - 1;
            if (!((rem0 >> i) & 1ull)) {    // uniform: rem identical on all lanes
                rem0 |= readlane64(B0, i); rem1 |= readlane64(B1, i);
                rem2 |= readlane64(B2, i); rem3 |= readlane64(B3, i);
                rem4 |= readlane64(B4, i);
            }
        }
    }
    {
        const ull* p = sSup + (size_t)(64 + lane) * 5;
        ull B0 = p[0], B1 = p[1], B2 = p[2], B3 = p[3], B4 = p[4];
        PIN64(B0); PIN64(B1); PIN64(B2); PIN64(B3); PIN64(B4);
        ull nz = __ballot((B0 | B1 | B2 | B3 | B4) != 0ull);
        while (nz) {
            int i = __builtin_ctzll(nz);
            nz &= nz - 1;
            if (!((rem1 >> i) & 1ull)) {
                rem0 |= readlane64(B0, i); rem1 |= readlane64(B1, i);
                rem2 |= readlane64(B2, i); rem3 |= readlane64(B3, i);
                rem4 |= readlane64(B4, i);
            }
        }
    }
    {
        const ull* p = sSup + (size_t)(128 + lane) * 5;
        ull B0 = p[0], B1 = p[1], B2 = p[2], B3 = p[3], B4 = p[4];
        PIN64(B0); PIN64(B1); PIN64(B2); PIN64(B3); PIN64(B4);
        ull nz = __ballot((B0 | B1 | B2 | B3 | B4) != 0ull);
        while (nz) {
            int i = __builtin_ctzll(nz);
            nz &= nz - 1;
            if (!((rem2 >> i) & 1ull)) {
                rem0 |= readlane64(B0, i); rem1 |= readlane64(B1, i);
                rem2 |= readlane64(B2, i); rem3 |= readlane64(B3, i);
                rem4 |= readlane64(B4, i);
            }
        }
    }
    {
        const ull* p = sSup + (size_t)(192 + lane) * 5;
        ull B0 = p[0], B1 = p[1], B2 = p[2], B3 = p[3], B4 = p[4];
        PIN64(B0); PIN64(B1); PIN64(B2); PIN64(B3); PIN64(B4);
        ull nz = __ballot((B0 | B1 | B2 | B3 | B4) != 0ull);
        while (nz) {
            int i = __builtin_ctzll(nz);
            nz &= nz - 1;
            if (!((rem3 >> i) & 1ull)) {
                rem0 |= readlane64(B0, i); rem1 |= readlane64(B1, i);
                rem2 |= readlane64(B2, i); rem3 |= readlane64(B3, i);
                rem4 |= readlane64(B4, i);
            }
        }
    }
    {
        const bool v4 = lane < (TOPK - 256);
        const ull* p = sSup + (size_t)(256 + (v4 ? lane : 0)) * 5;
        ull B0 = v4 ? p[0] : 0ull, B1 = v4 ? p[1] : 0ull, B2 = v4 ? p[2] : 0ull,
            B3 = v4 ? p[3] : 0ull, B4 = v4 ? p[4] : 0ull;
        PIN64(B0); PIN64(B1); PIN64(B2); PIN64(B3); PIN64(B4);
        ull nz = __ballot((B0 | B1 | B2 | B3 | B4) != 0ull);
        while (nz) {
            int i = __builtin_ctzll(nz);
            nz &= nz - 1;
            if (!((rem4 >> i) & 1ull)) {
                rem0 |= readlane64(B0, i); rem1 |= readlane64(B1, i);
                rem2 |= readlane64(B2, i); rem3 |= readlane64(B3, i);
                rem4 |= readlane64(B4, i);
            }
        }
    }

    float* outp = out + ((size_t)b * NC + c) * (TOPK * 6);
    auto write_row = [&](int w, ull remw) {
        int r = (w << 6) + lane;
        if (r < TOPK) {
            float x1 = 0.f, y1 = 0.f, x2 = 0.f, y2 = 0.f, vv = 0.f, cc = 0.f;
            if (r < numSel && ((~remw >> lane) & 1ull)) {
                float4 bb = sBox[r];
                x1 = bb.x; y1 = bb.y; x2 = bb.z; y2 = bb.w;
                vv = sVal[r]; cc = (float)c;
            }
            float* row = outp + r * 6;
            *(float2*)(row)     = float2{x1, y1};
            *(float2*)(row + 2) = float2{x2, y2};
            *(float2*)(row + 4) = float2{vv, cc};
        }
    };
    write_row(0, rem0);
    write_row(1, rem1);
    write_row(2, rem2);
    write_row(3, rem3);
    write_row(4, rem4);
}

extern "C" void kernel_launch(void* const* d_in, const int* in_sizes, int n_in,
                              void* d_out, int out_size, void* d_ws, size_t ws_size,
                              hipStream_t stream) {
    const float* in = (const float*)d_in[0];
    float* out = (float*)d_out;
    (void)d_ws; (void)ws_size;   // fused kernel keeps all intermediates in LDS

    k_fused<<<NTASK, NT, 0, stream>>>(in, out);
}

// Round 4
// 86.285 us; speedup vs baseline: 1.2487x; 1.2487x over previous
//
#include <hip/hip_runtime.h>
#include <cstdint>

#pragma clang fp contract(off)

#define NB      32
#define NC      18
#define NA      8400
#define NCH     (4 + NC)
#define NTASK   (NB * NC)      // 576
#define TOPK    300
#define TARGET  316        // TOPK + margin: absorbs sigmoid-tie rank ambiguity
#define NBINS   2048
#define CAP     1024
#define CONF    0.25f
#define IOU_T   0.45f
#define NT      512
#define NW      (NT / 64)
// Prefilter: N(0,1) logits, top-316 cutoff ~1.75 +- 0.1; count(x>1.4) in [553,803] (5-sigma).
// Fast path requires TARGET <= s_cnt <= CAP, else exact fallback.
#define PREF_X  1.4f
// sigmoid(x) > 0.25  <=>  x > -ln(3). Outside [XLO,XHI] analytic compare is exact.
#define XHI     (-1.0984f)
#define XLO     (-1.0988f)

// Fast-path binning: keys (mono_key of x>1.4) start at 0xBFB33333.
#define FAST_KBASE 0xBFB00000u
#define FAST_SHIFT 14
// Fallback binning: conf_pass keys start ~0x40735C26.
#define FB_KBASE   0x40000000u
#define FB_SHIFT   21

// Exact div-free IoU compare: RN_f32(inter/D) > 0.45f  <=>  inter > M45*D.
// M45 = fp32(0.45) + 2^-26 (25-bit mantissa, exact in f64; x 24-bit D -> exact
// 49-bit product). Tie rounds-to-even back to 0.45f => not >, matching. Bit-exact.
#define M45 (30198989.0 / 67108864.0)

typedef unsigned long long ull;

__device__ __forceinline__ float sigmoidf(float x) {
    return 1.0f / (1.0f + expf(-x));
}
__device__ __forceinline__ unsigned int mono_key(unsigned int bits) {
    return (bits & 0x80000000u) ? ~bits : (bits | 0x80000000u);
}
__device__ __forceinline__ unsigned int mono_inv(unsigned int key) {
    return (key & 0x80000000u) ? (key ^ 0x80000000u) : ~key;
}
__device__ __forceinline__ bool conf_pass(float x) {
    if (x >= XHI) return true;
    if (x <= XLO) return false;
    return sigmoidf(x) > CONF;   // rare exact band (~1 element per task)
}
__device__ __forceinline__ unsigned int make_key(float x) {
    return conf_pass(x) ? mono_key(__float_as_uint(x)) : 0u;
}
__device__ __forceinline__ ull readlane64(ull v, int i) {
    unsigned lo = (unsigned)__builtin_amdgcn_readlane((int)(unsigned)(v & 0xFFFFFFFFull), i);
    unsigned hi = (unsigned)__builtin_amdgcn_readlane((int)(unsigned)(v >> 32), i);
    return ((ull)hi << 32) | (ull)lo;
}

// Suffix-find over hist: T1 s.t. count(bins > T1) < target <= count(bins >= T1).
__device__ __forceinline__ void suffix_find(unsigned int* hist, unsigned int* wtot,
                                            int target, int tid, int* s_T1) {
    const int base = tid * (NBINS / NT);
    unsigned int v = 0;
#pragma unroll
    for (int k = 0; k < NBINS / NT; ++k) v += hist[base + k];
    const int lane = tid & 63;
    unsigned int s = v;
#pragma unroll
    for (int d = 1; d < 64; d <<= 1) {
        unsigned int o = __shfl_down(s, d, 64);
        if (lane + d < 64) s += o;
    }
    if (lane == 0) wtot[tid >> 6] = s;
    __syncthreads();
    unsigned int above_waves = 0;
    for (int wv = (tid >> 6) + 1; wv < NW; ++wv) above_waves += wtot[wv];
    unsigned int acc = (s - v) + above_waves;
    for (int bin = base + (NBINS / NT) - 1; bin >= base; --bin) {
        unsigned int cnt = hist[bin];
        if (acc < (unsigned int)target && acc + cnt >= (unsigned int)target) *s_T1 = bin;
        acc += cnt;
    }
    __syncthreads();
}

// Pool layout: [0,8192) hist -> cand2 -> sSup(12000B, spills into cand region)
// [8192,16384) cand. All reuses are barrier-separated.
#define OFF_CAND   8192
#define POOL1_BYTES 16384

// PIN: keep loaded mask words in VGPRs across the serial scan (compiler
// otherwise rematerializes the loads inside the scan loop).
#define PIN64(x) asm volatile("" : "+v"(x))

// ============ Fused: select -> rank -> compacted NMS -> output.
// One block per task; all intermediates in LDS.
// Data facts exploited: only ~25% of boxes have w>0 && h>0; area_i==0.0f
// => inter(i,j)==0.0f exactly (RN monotone) => zero-area rows neither
// suppress nor get suppressed. The ENTIRE NMS (mask build + greedy scan)
// runs in compacted active-row space (~75 rows): mask pairs 15k->5.6k,
// scan groups 5->~2. Compaction is rank-order-preserving, all fp
// expressions unchanged -> bit-exact. Rank is O(F^2) counting (R3 showed
// the barrier-heavy bitonic sort is SLOWER in this latency-bound regime). ============
__global__ __launch_bounds__(NT, 4) void k_fused(const float* __restrict__ in,
                                                 float* __restrict__ out) {
    __shared__ __align__(16) unsigned char pool[POOL1_BYTES];
    __shared__ __align__(16) float4 sBox[TOPK];
    __shared__ float sVal[TOPK];
    __shared__ float sAr[TOPK];
    __shared__ unsigned int wtot[NW];
    __shared__ unsigned short actIdx[TOPK];   // compacted pos -> row
    __shared__ unsigned short sPos[TOPK];     // row -> compacted pos
    __shared__ ull s_remC[5];                 // compacted suppressed bits
    __shared__ unsigned int s_cnt, s_cnt2, s_nAct;
    __shared__ int s_T1;

    unsigned int* hist = (unsigned int*)pool;
    ull* cand2 = (ull*)pool;
    ull* cand  = (ull*)(pool + OFF_CAND);
    ull* sSup  = (ull*)pool;              // valid after rank barrier

    const int tid = threadIdx.x;
    const int lane = tid & 63;
    const int wave = tid >> 6;
    const ull ltm = (1ull << lane) - 1ull;
    const int t = blockIdx.x;
    // XCD swizzle: image b -> XCD b%8
    const int b = (t & 7) + 8 * ((t >> 3) & 3);
    const int c = t >> 5;
    const float* cls = in + (size_t)b * NCH * NA + (size_t)(4 + c) * NA;
    const float* box = in + (size_t)b * NCH * NA;

    for (int i = tid; i < NBINS; i += NT) hist[i] = 0;
    // zero rows that select may leave unwritten (rank >= numSel)
    for (int r = tid; r < TOPK; r += NT) {
        sBox[r] = float4{0.f, 0.f, 0.f, 0.f};
        sVal[r] = 0.f;
        sAr[r] = 0.f;
    }
    if (tid == 0) { s_cnt = 0; s_cnt2 = 0; s_T1 = -1; }
    __syncthreads();

    // P1: prefilter x>1.4, wave-aggregated compaction, fused refine histogram.
    // 2-deep software prefetch hides most of the global-load latency.
    {
        const float4* cls4 = (const float4*)cls;
        int q = tid;                       // tid < NT <= NA/4: first load valid
        float4 v = cls4[q];
        while (true) {
            const int qn = q + NT;
            const bool more = qn < NA / 4;
            float4 vn;
            if (more) vn = cls4[qn];

            const unsigned int i0 = (unsigned int)q * 4u;
            float xs[4] = {v.x, v.y, v.z, v.w};
            ull m[4];
            unsigned int cnt = 0;
#pragma unroll
            for (int u = 0; u < 4; ++u) {
                m[u] = __ballot(xs[u] > PREF_X);
                cnt += (unsigned int)__popcll(m[u]);
            }
            if (cnt) {
                unsigned int base = 0;
                if (lane == 0) base = atomicAdd(&s_cnt, cnt);
                base = (unsigned int)__builtin_amdgcn_readfirstlane((int)base);
                unsigned int pre = 0;
#pragma unroll
                for (int u = 0; u < 4; ++u) {
                    if (xs[u] > PREF_X) {
                        unsigned int mk = mono_key(__float_as_uint(xs[u]));
                        atomicAdd(&hist[min((mk - FAST_KBASE) >> FAST_SHIFT,
                                            (unsigned)(NBINS - 1))], 1u);
                        unsigned int p = base + pre + (unsigned int)__popcll(m[u] & ltm);
                        if (p < CAP)
                            cand[p] = ((ull)mk << 32) | (ull)(~(i0 + u));
                    }
                    pre += (unsigned int)__popcll(m[u]);
                }
            }
            if (!more) break;
            v = vn; q = qn;
        }
    }
    __syncthreads();

    const int pcnt = (int)s_cnt;
    if (pcnt >= TARGET && pcnt <= CAP) {
        // ---- fast path ----
        suffix_find(hist, wtot, TARGET, tid, &s_T1);
        const ull thr = ((ull)FAST_KBASE + ((ull)(unsigned int)s_T1 << FAST_SHIFT)) << 32;
        const int iters = (pcnt + NT - 1) / NT;
        for (int it = 0; it < iters; ++it) {
            int e = tid + it * NT;
            bool act = e < pcnt;
            ull k = act ? cand[e] : 0ull;
            bool sel = act && (k >= thr);
            ull mb = __ballot(sel);
            unsigned int cnt = (unsigned int)__popcll(mb);
            if (cnt) {
                unsigned int basep = 0;
                if (lane == 0) basep = atomicAdd(&s_cnt2, cnt);
                basep = (unsigned int)__builtin_amdgcn_readfirstlane((int)basep);
                if (sel) {
                    float xv = __uint_as_float(mono_inv((unsigned int)(k >> 32)));
                    float sv = sigmoidf(xv);
                    unsigned int p = basep + (unsigned int)__popcll(mb & ltm);
                    if (p < CAP)
                        cand2[p] = ((ull)__float_as_uint(sv) << 32) | (k & 0xFFFFFFFFull);
                }
            }
        }
        __syncthreads();
    } else {
        // ---- exact fallback (rare): re-zero hist, full conf_pass histogram ----
        __syncthreads();
        for (int i = tid; i < NBINS; i += NT) hist[i] = 0;
        __syncthreads();
        {
            const float4* cls4 = (const float4*)cls;
            for (int q = tid; q < NA / 4; q += NT) {
                float4 v = cls4[q];
                unsigned int kx = make_key(v.x), ky = make_key(v.y);
                unsigned int kz = make_key(v.z), kw = make_key(v.w);
                if (kx) atomicAdd(&hist[min((kx - FB_KBASE) >> FB_SHIFT, (unsigned)(NBINS - 1))], 1u);
                if (ky) atomicAdd(&hist[min((ky - FB_KBASE) >> FB_SHIFT, (unsigned)(NBINS - 1))], 1u);
                if (kz) atomicAdd(&hist[min((kz - FB_KBASE) >> FB_SHIFT, (unsigned)(NBINS - 1))], 1u);
                if (kw) atomicAdd(&hist[min((kw - FB_KBASE) >> FB_SHIFT, (unsigned)(NBINS - 1))], 1u);
            }
        }
        __syncthreads();
        suffix_find(hist, wtot, TARGET, tid, &s_T1);
        {
            const ull thr = (s_T1 < 0) ? 0ull
                : ((ull)FB_KBASE + ((ull)(unsigned int)s_T1 << FB_SHIFT));
            const float4* cls4 = (const float4*)cls;
            for (int q = tid; q < NA / 4; q += NT) {
                float4 v = cls4[q];
                const unsigned int i0 = (unsigned int)q * 4u;
                float xs[4] = {v.x, v.y, v.z, v.w};
#pragma unroll
                for (int u = 0; u < 4; ++u) {
                    unsigned int d = make_key(xs[u]);
                    if (d && (ull)d >= thr) {
                        unsigned int p = atomicAdd(&s_cnt2, 1u);
                        if (p < CAP) {
                            float sv = sigmoidf(xs[u]);
                            cand2[p] = ((ull)__float_as_uint(sv) << 32) | (ull)(~(i0 + u));
                        }
                    }
                }
            }
        }
        __syncthreads();
    }

    const int F = min((int)s_cnt2, CAP);
    const int numSel = min(F, TOPK);

    // rank-by-counting (unique keys via ~idx) + FUSED box gather -> LDS.
    // Box gather loads issued BEFORE the O(F) scan so their ~900cy scattered
    // HBM latency hides under the compare loop (values used only at the end).
    for (int e = tid; e < F; e += NT) {
        ull k = cand2[e];
        unsigned int i = ~(unsigned int)(k & 0xFFFFFFFFull);
        float cx = box[i];
        float cy = box[NA + i];
        float w  = box[2 * NA + i];
        float h  = box[3 * NA + i];
        int rank = 0;
        int o = 0;
#pragma unroll 2
        for (; o + 4 <= F; o += 4) {
            ulonglong2 p0 = *(const ulonglong2*)&cand2[o];
            ulonglong2 p1 = *(const ulonglong2*)&cand2[o + 2];
            rank += (p0.x > k) + (p0.y > k) + (p1.x > k) + (p1.y > k);
        }
        for (; o < F; ++o) rank += (cand2[o] > k) ? 1 : 0;
        if (rank < TOPK) {
            float hw = w * 0.5f, hh = h * 0.5f;
            float x1 = cx - hw, y1 = cy - hh, x2 = cx + hw, y2 = cy + hh;
            sBox[rank] = float4{x1, y1, x2, y2};
            sVal[rank] = __uint_as_float((unsigned int)(k >> 32));
            sAr[rank] = fmaxf(x2 - x1, 0.f) * fmaxf(y2 - y1, 0.f);
        }
    }
    __syncthreads();   // cand2 dead from here; pool becomes sSup

    // ---- zero sSup + order-preserving compaction of active rows ----
    for (int i = tid; i < TOPK * 5; i += NT) sSup[i] = 0ull;
    {
        int r = tid;
        bool act = (r < TOPK) && (r < numSel) && (sAr[r] > 0.0f);
        ull mb = __ballot(act);
        if (lane == 0) wtot[wave] = (unsigned int)__popcll(mb);
        __syncthreads();
        unsigned int basew = 0;
        for (int w2 = 0; w2 < wave; ++w2) basew += wtot[w2];
        if (tid == 0) {
            unsigned int tot = 0;
            for (int w2 = 0; w2 < NW; ++w2) tot += wtot[w2];
            s_nAct = tot;
        }
        if (act) {
            unsigned int p = basew + (unsigned int)__popcll(mb & ltm);
            actIdx[p] = (unsigned short)r;
            sPos[r] = (unsigned short)p;
        }
    }
    __syncthreads();
    const int nAct = (int)s_nAct;

    // ---- suppression-mask build in COMPACTED space (~75 rows, ~2 words) ----
    {
        float4 cb[5];
        float ca[5];
#pragma unroll
        for (int w = 0; w < 5; ++w) {
            int jc = (w << 6) + lane;
            bool v = jc < nAct;
            int j = v ? (int)actIdx[jc] : 0;
            cb[w] = v ? sBox[j] : float4{0.f, 0.f, 0.f, 0.f};
            ca[w] = v ? sAr[j] : 0.f;
        }
        const int wlast = (nAct > 0) ? ((nAct - 1) >> 6) : -1;
        for (int p = wave; p < nAct; p += NW) {
            int r = actIdx[p];
            float4 bi = sBox[r];
            float ai = sAr[r];
            const int w0 = p >> 6;
#pragma unroll
            for (int w = 0; w < 5; ++w) {
                if (w >= w0 && w <= wlast) {   // uniform branch
                    const int jc = (w << 6) + lane;
                    bool supb = false;
                    if (jc < nAct && jc > p) {
                        float xx1 = fmaxf(bi.x, cb[w].x);
                        float yy1 = fmaxf(bi.y, cb[w].y);
                        float xx2 = fminf(bi.z, cb[w].z);
                        float yy2 = fminf(bi.w, cb[w].w);
                        float iw = fmaxf(xx2 - xx1, 0.0f);
                        float ih = fmaxf(yy2 - yy1, 0.0f);
                        float inter = iw * ih;
                        float un = ai + ca[w] - inter;
                        float D = fmaxf(un, 1e-9f);
                        supb = (double)inter > M45 * (double)D;  // == RN(inter/D) > 0.45f
                    }
                    ull bal = __ballot(supb);
                    if (lane == 0) sSup[p * 5 + w] = bal;
                }
            }
        }
    }
    __syncthreads();

    // ---- greedy scan over compacted rows (wave 0). Rows >= nAct have zero
    // words (pre-zeroed) -> nz-skip handles them for free. ----
    if (wave == 0) {
        ull rem0 = 0, rem1 = 0, rem2 = 0, rem3 = 0, rem4 = 0;
        {
            const ull* p = sSup + (size_t)lane * 5;
            ull B0 = p[0], B1 = p[1], B2 = p[2], B3 = p[3], B4 = p[4];
            PIN64(B0); PIN64(B1); PIN64(B2); PIN64(B3); PIN64(B4);
            ull nz = __ballot((B0 | B1 | B2 | B3 | B4) != 0ull);
            while (nz) {
                int i = __builtin_ctzll(nz);
                nz &= nz - 1;
                if (!((rem0 >> i) & 1ull)) {    // uniform: rem identical on all lanes
                    rem0 |= readlane64(B0, i); rem1 |= readlane64(B1, i);
                    rem2 |= readlane64(B2, i); rem3 |= readlane64(B3, i);
                    rem4 |= readlane64(B4, i);
                }
            }
        }
        if (nAct > 64) {
            const ull* p = sSup + (size_t)(64 + lane) * 5;
            ull B0 = p[0], B1 = p[1], B2 = p[2], B3 = p[3], B4 = p[4];
            PIN64(B0); PIN64(B1); PIN64(B2); PIN64(B3); PIN64(B4);
            ull nz = __ballot((B0 | B1 | B2 | B3 | B4) != 0ull);
            while (nz) {
                int i = __builtin_ctzll(nz);
                nz &= nz - 1;
                if (!((rem1 >> i) & 1ull)) {
                    rem0 |= readlane64(B0, i); rem1 |= readlane64(B1, i);
                    rem2 |= readlane64(B2, i); rem3 |= readlane64(B3, i);
                    rem4 |= readlane64(B4, i);
                }
            }
        }
        if (nAct > 128) {
            const ull* p = sSup + (size_t)(128 + lane) * 5;
            ull B0 = p[0], B1 = p[1], B2 = p[2], B3 = p[3], B4 = p[4];
            PIN64(B0); PIN64(B1); PIN64(B2); PIN64(B3); PIN64(B4);
            ull nz = __ballot((B0 | B1 | B2 | B3 | B4) != 0ull);
            while (nz) {
                int i = __builtin_ctzll(nz);
                nz &= nz - 1;
                if (!((rem2 >> i) & 1ull)) {
                    rem0 |= readlane64(B0, i); rem1 |= readlane64(B1, i);
                    rem2 |= readlane64(B2, i); rem3 |= readlane64(B3, i);
                    rem4 |= readlane64(B4, i);
                }
            }
        }
        if (nAct > 192) {
            const ull* p = sSup + (size_t)(192 + lane) * 5;
            ull B0 = p[0], B1 = p[1], B2 = p[2], B3 = p[3], B4 = p[4];
            PIN64(B0); PIN64(B1); PIN64(B2); PIN64(B3); PIN64(B4);
            ull nz = __ballot((B0 | B1 | B2 | B3 | B4) != 0ull);
            while (nz) {
                int i = __builtin_ctzll(nz);
                nz &= nz - 1;
                if (!((rem3 >> i) & 1ull)) {
                    rem0 |= readlane64(B0, i); rem1 |= readlane64(B1, i);
                    rem2 |= readlane64(B2, i); rem3 |= readlane64(B3, i);
                    rem4 |= readlane64(B4, i);
                }
            }
        }
        if (nAct > 256) {
            const bool v4 = lane < (TOPK - 256);
            const ull* p = sSup + (size_t)(256 + (v4 ? lane : 0)) * 5;
            ull B0 = v4 ? p[0] : 0ull, B1 = v4 ? p[1] : 0ull, B2 = v4 ? p[2] : 0ull,
                B3 = v4 ? p[3] : 0ull, B4 = v4 ? p[4] : 0ull;
            PIN64(B0); PIN64(B1); PIN64(B2); PIN64(B3); PIN64(B4);
            ull nz = __ballot((B0 | B1 | B2 | B3 | B4) != 0ull);
            while (nz) {
                int i = __builtin_ctzll(nz);
                nz &= nz - 1;
                if (!((rem4 >> i) & 1ull)) {
                    rem0 |= readlane64(B0, i); rem1 |= readlane64(B1, i);
                    rem2 |= readlane64(B2, i); rem3 |= readlane64(B3, i);
                    rem4 |= readlane64(B4, i);
                }
            }
        }
        if (lane == 0) {
            s_remC[0] = rem0; s_remC[1] = rem1; s_remC[2] = rem2;
            s_remC[3] = rem3; s_remC[4] = rem4;
        }
    }
    __syncthreads();

    // ---- output: thread r writes row r (coalesced 24B/thread). Inactive
    // (zero-area) rows are never suppressed -> kept; active rows look up
    // their compacted suppressed bit. ----
    {
        const int r = tid;
        if (r < TOPK) {
            float x1 = 0.f, y1 = 0.f, x2 = 0.f, y2 = 0.f, vv = 0.f, cc = 0.f;
            if (r < numSel) {
                bool sup = false;
                if (sAr[r] > 0.0f) {
                    int p = (int)sPos[r];
                    sup = (s_remC[p >> 6] >> (p & 63)) & 1ull;
                }
                if (!sup) {
                    float4 bb = sBox[r];
                    x1 = bb.x; y1 = bb.y; x2 = bb.z; y2 = bb.w;
                    vv = sVal[r]; cc = (float)c;
                }
            }
            float* outp = out + ((size_t)b * NC + c) * (TOPK * 6);
            float* row = outp + r * 6;
            *(float2*)(row)     = float2{x1, y1};
            *(float2*)(row + 2) = float2{x2, y2};
            *(float2*)(row + 4) = float2{vv, cc};
        }
    }
}

extern "C" void kernel_launch(void* const* d_in, const int* in_sizes, int n_in,
                              void* d_out, int out_size, void* d_ws, size_t ws_size,
                              hipStream_t stream) {
    const float* in = (const float*)d_in[0];
    float* out = (float*)d_out;
    (void)d_ws; (void)ws_size;   // fused kernel keeps all intermediates in LDS

    k_fused<<<NTASK, NT, 0, stream>>>(in, out);
}

// Round 5
// 82.660 us; speedup vs baseline: 1.3035x; 1.0438x over previous
//
#include <hip/hip_runtime.h>
#include <cstdint>

#pragma clang fp contract(off)

#define NB      32
#define NC      18
#define NA      8400
#define NCH     (4 + NC)
#define NTASK   (NB * NC)      // 576
#define TOPK    300
#define TARGET  316        // fast path needs pcnt >= TOPK; 316 keeps margin
#define NBINS   2048
#define CAP     1024
#define CONF    0.25f
#define IOU_T   0.45f
#define NT      512
#define NW      (NT / 64)
// Prefilter: N(0,1) logits, top-316 cutoff ~1.75 +- 0.1; count(x>1.4) in [553,803] (5-sigma).
// Fast path requires TARGET <= pcnt <= CAP, else exact fallback.
#define PREF_X  1.4f
// sigmoid(x) > 0.25  <=>  x > -ln(3). Outside [XLO,XHI] analytic compare is exact.
#define XHI     (-1.0984f)
#define XLO     (-1.0988f)

// Fast-path binning is on SIGMOID bits (positive floats: raw bits monotone).
// x>1.4 => sv > 0.80218 => bits >= 0x3F4D6049 > SV_KBASE. sv<=1.0 => bin<=1632<NBINS.
#define SV_KBASE 0x3F4D0000u
#define SV_SHIFT 11
// Fallback binning: conf_pass x-mono-keys start ~0x40735C26.
#define FB_KBASE   0x40000000u
#define FB_SHIFT   21

// Exact div-free IoU compare: RN_f32(inter/D) > 0.45f  <=>  inter > M45*D.
// M45 = fp32(0.45) + 2^-26 (25-bit mantissa, exact in f64; x 24-bit D -> exact
// 49-bit product). Tie rounds-to-even back to 0.45f => not >, matching. Bit-exact.
#define M45 (30198989.0 / 67108864.0)

typedef unsigned long long ull;

__device__ __forceinline__ float sigmoidf(float x) {
    return 1.0f / (1.0f + expf(-x));
}
__device__ __forceinline__ unsigned int mono_key(unsigned int bits) {
    return (bits & 0x80000000u) ? ~bits : (bits | 0x80000000u);
}
__device__ __forceinline__ bool conf_pass(float x) {
    if (x >= XHI) return true;
    if (x <= XLO) return false;
    return sigmoidf(x) > CONF;   // rare exact band (~1 element per task)
}
__device__ __forceinline__ unsigned int make_key(float x) {
    return conf_pass(x) ? mono_key(__float_as_uint(x)) : 0u;
}
__device__ __forceinline__ ull readlane64(ull v, int i) {
    unsigned lo = (unsigned)__builtin_amdgcn_readlane((int)(unsigned)(v & 0xFFFFFFFFull), i);
    unsigned hi = (unsigned)__builtin_amdgcn_readlane((int)(unsigned)(v >> 32), i);
    return ((ull)hi << 32) | (ull)lo;
}

// Suffix-find over hist: T1 s.t. count(bins > T1) < target <= count(bins >= T1).
// (fallback path only)
__device__ __forceinline__ void suffix_find(unsigned int* hist, unsigned int* wtot,
                                            int target, int tid, int* s_T1) {
    const int base = tid * (NBINS / NT);
    unsigned int v = 0;
#pragma unroll
    for (int k = 0; k < NBINS / NT; ++k) v += hist[base + k];
    const int lane = tid & 63;
    unsigned int s = v;
#pragma unroll
    for (int d = 1; d < 64; d <<= 1) {
        unsigned int o = __shfl_down(s, d, 64);
        if (lane + d < 64) s += o;
    }
    if (lane == 0) wtot[tid >> 6] = s;
    __syncthreads();
    unsigned int above_waves = 0;
    for (int wv = (tid >> 6) + 1; wv < NW; ++wv) above_waves += wtot[wv];
    unsigned int acc = (s - v) + above_waves;
    for (int bin = base + (NBINS / NT) - 1; bin >= base; --bin) {
        unsigned int cnt = hist[bin];
        if (acc < (unsigned int)target && acc + cnt >= (unsigned int)target) *s_T1 = bin;
        acc += cnt;
    }
    __syncthreads();
}

// Pool layout: [0,8192) hist (-> cand2 in fallback -> sSup) ; [8192,16384) cand
// (-> sorted). All reuses are barrier-separated.
#define OFF_CAND   8192
#define POOL1_BYTES 16384

// PIN: keep loaded mask words in VGPRs across the serial scan (compiler
// otherwise rematerializes the loads inside the scan loop).
#define PIN64(x) asm volatile("" : "+v"(x))

// ============ Fused: select -> counting-sort rank -> compacted NMS -> output.
// One block per task; all intermediates in LDS.
// (1) Rank via EXACT counting sort on sigmoid-bit keys: P1 histograms sv-bins
//     (atomic return = within-bin slot); a block suffix-scan gives S[bin] =
//     #keys in strictly-greater bins; scatter to sorted[S+slot]; final rank =
//     S[bin] + #(bin-mates with (sv,~idx) key greater). Identical descending
//     (sv,~idx) order as rank-by-counting -> bit-exact, at O(F) instead of
//     O(F^2) (the R2-R4 quadratic loop was the largest VALU phase).
// (2) Zero-area rows (~75%: w<=0 or h<=0) provably have inter==0.0f vs all
//     boxes -> NMS runs in compacted active-row space (~75 rows).
// (3) sBox/sVal/sAr need no zero-init: every read is r<numSel-guarded and
//     ranks 0..numSel-1 are each written exactly once (unique-key bijection).
__global__ __launch_bounds__(NT, 4) void k_fused(const float* __restrict__ in,
                                                 float* __restrict__ out) {
    __shared__ __align__(16) unsigned char pool[POOL1_BYTES];
    __shared__ __align__(16) float4 sBox[TOPK];
    __shared__ float sVal[TOPK];
    __shared__ float sAr[TOPK];
    __shared__ unsigned int S[NBINS];         // suffix counts (fast path)
    __shared__ unsigned short slotArr[CAP];   // within-bin arrival slot
    __shared__ unsigned int wtot[NW];
    __shared__ unsigned short actIdx[TOPK];   // compacted pos -> row
    __shared__ unsigned short sPos[TOPK];     // row -> compacted pos
    __shared__ ull s_remC[5];                 // compacted suppressed bits
    __shared__ unsigned int s_cnt, s_cnt2, s_nAct;
    __shared__ int s_T1;

    unsigned int* hist = (unsigned int*)pool;
    ull* cand   = (ull*)(pool + OFF_CAND);
    ull* sorted = (ull*)(pool + OFF_CAND);  // overlays cand, barrier-separated
    ull* cand2  = (ull*)pool;               // fallback only
    ull* sSup   = (ull*)pool;               // valid after rank barrier

    const int tid = threadIdx.x;
    const int lane = tid & 63;
    const int wave = tid >> 6;
    const ull ltm = (1ull << lane) - 1ull;
    const int t = blockIdx.x;
    // XCD swizzle: image b -> XCD b%8 (18 class-tasks of an image share box rows in L2)
    const int b = (t & 7) + 8 * ((t >> 3) & 3);
    const int c = t >> 5;
    const float* cls = in + (size_t)b * NCH * NA + (size_t)(4 + c) * NA;
    const float* box = in + (size_t)b * NCH * NA;

    // issue first two P1 loads BEFORE LDS init (latency hides under zeroing)
    const float4* cls4 = (const float4*)cls;
    float4 v  = cls4[tid];              // tid < 512 <= 2100: valid
    float4 vn = cls4[tid + NT];         // tid+512 <= 1023 < 2100: valid

    for (int i = tid; i < NBINS; i += NT) hist[i] = 0;
    if (tid == 0) { s_cnt = 0; s_cnt2 = 0; s_T1 = -1; }
    __syncthreads();

    // P1: prefilter x>1.4, wave-aggregated compaction; sv computed here; sv-bin
    // histogram (atomic return = slot). 2-deep rolling prefetch.
    for (int q = tid; q < NA / 4; q += NT) {
        const int qpp = q + 2 * NT;
        float4 vf;
        const bool havef = qpp < NA / 4;
        if (havef) vf = cls4[qpp];

        const unsigned int i0 = (unsigned int)q * 4u;
        float xs[4] = {v.x, v.y, v.z, v.w};
        ull m[4];
        unsigned int cnt = 0;
#pragma unroll
        for (int u = 0; u < 4; ++u) {
            m[u] = __ballot(xs[u] > PREF_X);
            cnt += (unsigned int)__popcll(m[u]);
        }
        if (cnt) {
            unsigned int base = 0;
            if (lane == 0) base = atomicAdd(&s_cnt, cnt);
            base = (unsigned int)__builtin_amdgcn_readfirstlane((int)base);
            unsigned int pre = 0;
#pragma unroll
            for (int u = 0; u < 4; ++u) {
                if (xs[u] > PREF_X) {
                    float sv = sigmoidf(xs[u]);
                    unsigned int svb = __float_as_uint(sv);
                    unsigned int bin = min((svb - SV_KBASE) >> SV_SHIFT,
                                           (unsigned)(NBINS - 1));
                    unsigned int slot = atomicAdd(&hist[bin], 1u);
                    unsigned int p = base + pre + (unsigned int)__popcll(m[u] & ltm);
                    if (p < CAP) {
                        cand[p] = ((ull)svb << 32) | (ull)(~(i0 + u));
                        slotArr[p] = (unsigned short)slot;
                    }
                }
                pre += (unsigned int)__popcll(m[u]);
            }
        }
        v = vn; vn = vf;
    }
    __syncthreads();

    const int pcnt = (int)s_cnt;
    int numSel;
    if (pcnt >= TARGET && pcnt <= CAP) {
        // ================= fast path: exact counting-sort rank =================
        numSel = TOPK;    // pcnt >= 316 > 300

        // suffix-scan: S[bin] = # keys in bins strictly greater than bin
        {
            const int basebin = tid * (NBINS / NT);
            unsigned int cs[NBINS / NT];
            unsigned int vsum = 0;
#pragma unroll
            for (int k = 0; k < NBINS / NT; ++k) { cs[k] = hist[basebin + k]; vsum += cs[k]; }
            unsigned int s = vsum;
#pragma unroll
            for (int d = 1; d < 64; d <<= 1) {
                unsigned int o = __shfl_down(s, d, 64);
                if (lane + d < 64) s += o;
            }
            if (lane == 0) wtot[wave] = s;
            __syncthreads();
            unsigned int above = 0;
            for (int w2 = wave + 1; w2 < NW; ++w2) above += wtot[w2];
            unsigned int acc = (s - vsum) + above;
#pragma unroll
            for (int k = NBINS / NT - 1; k >= 0; --k) { S[basebin + k] = acc; acc += cs[k]; }
        }
        __syncthreads();

        // stage: read my <=2 candidates (key, slot, S[bin], hist[bin]) into regs
        // and ISSUE the scattered box-gather loads now (latency hides under the
        // scatter barriers below).
        ull k0 = 0, k1 = 0;
        unsigned int pos0 = 0, pos1 = 0, g0 = 0, g1 = 0, c0 = 0, c1 = 0;
        const bool a0 = tid < pcnt, a1 = tid + NT < pcnt;
        float cx0 = 0.f, cy0 = 0.f, w0 = 0.f, h0 = 0.f;
        float cx1 = 0.f, cy1 = 0.f, w1 = 0.f, h1 = 0.f;
        if (a0) {
            k0 = cand[tid];
            unsigned int svb = (unsigned int)(k0 >> 32);
            unsigned int bin = min((svb - SV_KBASE) >> SV_SHIFT, (unsigned)(NBINS - 1));
            g0 = S[bin]; c0 = hist[bin];
            pos0 = g0 + (unsigned int)slotArr[tid];
            unsigned int i = ~(unsigned int)(k0 & 0xFFFFFFFFull);
            cx0 = box[i]; cy0 = box[NA + i]; w0 = box[2 * NA + i]; h0 = box[3 * NA + i];
        }
        if (a1) {
            k1 = cand[tid + NT];
            unsigned int svb = (unsigned int)(k1 >> 32);
            unsigned int bin = min((svb - SV_KBASE) >> SV_SHIFT, (unsigned)(NBINS - 1));
            g1 = S[bin]; c1 = hist[bin];
            pos1 = g1 + (unsigned int)slotArr[tid + NT];
            unsigned int i = ~(unsigned int)(k1 & 0xFFFFFFFFull);
            cx1 = box[i]; cy1 = box[NA + i]; w1 = box[2 * NA + i]; h1 = box[3 * NA + i];
        }
        __syncthreads();      // all cand reads done; sorted overlays cand

        if (a0) sorted[pos0] = k0;
        if (a1) sorted[pos1] = k1;
        __syncthreads();

        // final rank = S[bin] + #(bin-mates with greater key); gather-write
        if (a0) {
            int rank = (int)g0;
            for (unsigned int j = g0; j < g0 + c0; ++j) rank += (sorted[j] > k0) ? 1 : 0;
            if (rank < TOPK) {
                float hw = w0 * 0.5f, hh = h0 * 0.5f;
                float x1 = cx0 - hw, y1 = cy0 - hh, x2 = cx0 + hw, y2 = cy0 + hh;
                sBox[rank] = float4{x1, y1, x2, y2};
                sVal[rank] = __uint_as_float((unsigned int)(k0 >> 32));
                sAr[rank] = fmaxf(x2 - x1, 0.f) * fmaxf(y2 - y1, 0.f);
            }
        }
        if (a1) {
            int rank = (int)g1;
            for (unsigned int j = g1; j < g1 + c1; ++j) rank += (sorted[j] > k1) ? 1 : 0;
            if (rank < TOPK) {
                float hw = w1 * 0.5f, hh = h1 * 0.5f;
                float x1 = cx1 - hw, y1 = cy1 - hh, x2 = cx1 + hw, y2 = cy1 + hh;
                sBox[rank] = float4{x1, y1, x2, y2};
                sVal[rank] = __uint_as_float((unsigned int)(k1 >> 32));
                sAr[rank] = fmaxf(x2 - x1, 0.f) * fmaxf(y2 - y1, 0.f);
            }
        }
        __syncthreads();      // sorted dead; pool -> sSup
    } else {
        // ---- exact fallback (rare): re-zero hist, full conf_pass histogram,
        // threshold, then O(F^2) rank-by-counting (verbatim from R4). ----
        __syncthreads();
        for (int i = tid; i < NBINS; i += NT) hist[i] = 0;
        __syncthreads();
        {
            for (int q = tid; q < NA / 4; q += NT) {
                float4 vq = cls4[q];
                unsigned int kx = make_key(vq.x), ky = make_key(vq.y);
                unsigned int kz = make_key(vq.z), kw = make_key(vq.w);
                if (kx) atomicAdd(&hist[min((kx - FB_KBASE) >> FB_SHIFT, (unsigned)(NBINS - 1))], 1u);
                if (ky) atomicAdd(&hist[min((ky - FB_KBASE) >> FB_SHIFT, (unsigned)(NBINS - 1))], 1u);
                if (kz) atomicAdd(&hist[min((kz - FB_KBASE) >> FB_SHIFT, (unsigned)(NBINS - 1))], 1u);
                if (kw) atomicAdd(&hist[min((kw - FB_KBASE) >> FB_SHIFT, (unsigned)(NBINS - 1))], 1u);
            }
        }
        __syncthreads();
        suffix_find(hist, wtot, TARGET, tid, &s_T1);
        {
            const ull thr = (s_T1 < 0) ? 0ull
                : ((ull)FB_KBASE + ((ull)(unsigned int)s_T1 << FB_SHIFT));
            for (int q = tid; q < NA / 4; q += NT) {
                float4 vq = cls4[q];
                const unsigned int i0 = (unsigned int)q * 4u;
                float xs[4] = {vq.x, vq.y, vq.z, vq.w};
#pragma unroll
                for (int u = 0; u < 4; ++u) {
                    unsigned int d = make_key(xs[u]);
                    if (d && (ull)d >= thr) {
                        unsigned int p = atomicAdd(&s_cnt2, 1u);
                        if (p < CAP) {
                            float sv = sigmoidf(xs[u]);
                            cand2[p] = ((ull)__float_as_uint(sv) << 32) | (ull)(~(i0 + u));
                        }
                    }
                }
            }
        }
        __syncthreads();
        const int F = min((int)s_cnt2, CAP);
        numSel = min(F, TOPK);
        for (int e = tid; e < F; e += NT) {
            ull k = cand2[e];
            unsigned int i = ~(unsigned int)(k & 0xFFFFFFFFull);
            float cx = box[i];
            float cy = box[NA + i];
            float w  = box[2 * NA + i];
            float h  = box[3 * NA + i];
            int rank = 0;
            int o = 0;
#pragma unroll 2
            for (; o + 4 <= F; o += 4) {
                ulonglong2 p0 = *(const ulonglong2*)&cand2[o];
                ulonglong2 p1 = *(const ulonglong2*)&cand2[o + 2];
                rank += (p0.x > k) + (p0.y > k) + (p1.x > k) + (p1.y > k);
            }
            for (; o < F; ++o) rank += (cand2[o] > k) ? 1 : 0;
            if (rank < TOPK) {
                float hw = w * 0.5f, hh = h * 0.5f;
                float x1 = cx - hw, y1 = cy - hh, x2 = cx + hw, y2 = cy + hh;
                sBox[rank] = float4{x1, y1, x2, y2};
                sVal[rank] = __uint_as_float((unsigned int)(k >> 32));
                sAr[rank] = fmaxf(x2 - x1, 0.f) * fmaxf(y2 - y1, 0.f);
            }
        }
        __syncthreads();      // cand2 dead; pool -> sSup
    }

    // ---- zero sSup + order-preserving compaction of active rows ----
    for (int i = tid; i < TOPK * 5; i += NT) sSup[i] = 0ull;
    {
        int r = tid;
        bool act = (r < TOPK) && (r < numSel) && (sAr[r] > 0.0f);
        ull mb = __ballot(act);
        if (lane == 0) wtot[wave] = (unsigned int)__popcll(mb);
        __syncthreads();
        unsigned int basew = 0;
        for (int w2 = 0; w2 < wave; ++w2) basew += wtot[w2];
        if (tid == 0) {
            unsigned int tot = 0;
            for (int w2 = 0; w2 < NW; ++w2) tot += wtot[w2];
            s_nAct = tot;
        }
        if (act) {
            unsigned int p = basew + (unsigned int)__popcll(mb & ltm);
            actIdx[p] = (unsigned short)r;
            sPos[r] = (unsigned short)p;
        }
    }
    __syncthreads();
    const int nAct = (int)s_nAct;

    // ---- suppression-mask build in COMPACTED space (~75 rows, ~2 words) ----
    {
        float4 cb[5];
        float ca[5];
#pragma unroll
        for (int w = 0; w < 5; ++w) {
            int jc = (w << 6) + lane;
            bool vv = jc < nAct;
            int j = vv ? (int)actIdx[jc] : 0;
            cb[w] = vv ? sBox[j] : float4{0.f, 0.f, 0.f, 0.f};
            ca[w] = vv ? sAr[j] : 0.f;
        }
        const int wlast = (nAct > 0) ? ((nAct - 1) >> 6) : -1;
        for (int p = wave; p < nAct; p += NW) {
            int r = actIdx[p];
            float4 bi = sBox[r];
            float ai = sAr[r];
            const int w0 = p >> 6;
#pragma unroll
            for (int w = 0; w < 5; ++w) {
                if (w >= w0 && w <= wlast) {   // uniform branch
                    const int jc = (w << 6) + lane;
                    bool supb = false;
                    if (jc < nAct && jc > p) {
                        float xx1 = fmaxf(bi.x, cb[w].x);
                        float yy1 = fmaxf(bi.y, cb[w].y);
                        float xx2 = fminf(bi.z, cb[w].z);
                        float yy2 = fminf(bi.w, cb[w].w);
                        float iw = fmaxf(xx2 - xx1, 0.0f);
                        float ih = fmaxf(yy2 - yy1, 0.0f);
                        float inter = iw * ih;
                        float un = ai + ca[w] - inter;
                        float D = fmaxf(un, 1e-9f);
                        supb = (double)inter > M45 * (double)D;  // == RN(inter/D) > 0.45f
                    }
                    ull bal = __ballot(supb);
                    if (lane == 0) sSup[p * 5 + w] = bal;
                }
            }
        }
    }
    __syncthreads();

    // ---- greedy scan over compacted rows (wave 0). Rows >= nAct have zero
    // words (pre-zeroed) -> nz-skip handles them for free. ----
    if (wave == 0) {
        ull rem0 = 0, rem1 = 0, rem2 = 0, rem3 = 0, rem4 = 0;
        {
            const ull* p = sSup + (size_t)lane * 5;
            ull B0 = p[0], B1 = p[1], B2 = p[2], B3 = p[3], B4 = p[4];
            PIN64(B0); PIN64(B1); PIN64(B2); PIN64(B3); PIN64(B4);
            ull nz = __ballot((B0 | B1 | B2 | B3 | B4) != 0ull);
            while (nz) {
                int i = __builtin_ctzll(nz);
                nz &= nz - 1;
                if (!((rem0 >> i) & 1ull)) {    // uniform: rem identical on all lanes
                    rem0 |= readlane64(B0, i); rem1 |= readlane64(B1, i);
                    rem2 |= readlane64(B2, i); rem3 |= readlane64(B3, i);
                    rem4 |= readlane64(B4, i);
                }
            }
        }
        if (nAct > 64) {
            const ull* p = sSup + (size_t)(64 + lane) * 5;
            ull B0 = p[0], B1 = p[1], B2 = p[2], B3 = p[3], B4 = p[4];
            PIN64(B0); PIN64(B1); PIN64(B2); PIN64(B3); PIN64(B4);
            ull nz = __ballot((B0 | B1 | B2 | B3 | B4) != 0ull);
            while (nz) {
                int i = __builtin_ctzll(nz);
                nz &= nz - 1;
                if (!((rem1 >> i) & 1ull)) {
                    rem0 |= readlane64(B0, i); rem1 |= readlane64(B1, i);
                    rem2 |= readlane64(B2, i); rem3 |= readlane64(B3, i);
                    rem4 |= readlane64(B4, i);
                }
            }
        }
        if (nAct > 128) {
            const ull* p = sSup + (size_t)(128 + lane) * 5;
            ull B0 = p[0], B1 = p[1], B2 = p[2], B3 = p[3], B4 = p[4];
            PIN64(B0); PIN64(B1); PIN64(B2); PIN64(B3); PIN64(B4);
            ull nz = __ballot((B0 | B1 | B2 | B3 | B4) != 0ull);
            while (nz) {
                int i = __builtin_ctzll(nz);
                nz &= nz - 1;
                if (!((rem2 >> i) & 1ull)) {
                    rem0 |= readlane64(B0, i); rem1 |= readlane64(B1, i);
                    rem2 |= readlane64(B2, i); rem3 |= readlane64(B3, i);
                    rem4 |= readlane64(B4, i);
                }
            }
        }
        if (nAct > 192) {
            const ull* p = sSup + (size_t)(192 + lane) * 5;
            ull B0 = p[0], B1 = p[1], B2 = p[2], B3 = p[3], B4 = p[4];
            PIN64(B0); PIN64(B1); PIN64(B2); PIN64(B3); PIN64(B4);
            ull nz = __ballot((B0 | B1 | B2 | B3 | B4) != 0ull);
            while (nz) {
                int i = __builtin_ctzll(nz);
                nz &= nz - 1;
                if (!((rem3 >> i) & 1ull)) {
                    rem0 |= readlane64(B0, i); rem1 |= readlane64(B1, i);
                    rem2 |= readlane64(B2, i); rem3 |= readlane64(B3, i);
                    rem4 |= readlane64(B4, i);
                }
            }
        }
        if (nAct > 256) {
            const bool v4 = lane < (TOPK - 256);
            const ull* p = sSup + (size_t)(256 + (v4 ? lane : 0)) * 5;
            ull B0 = v4 ? p[0] : 0ull, B1 = v4 ? p[1] : 0ull, B2 = v4 ? p[2] : 0ull,
                B3 = v4 ? p[3] : 0ull, B4 = v4 ? p[4] : 0ull;
            PIN64(B0); PIN64(B1); PIN64(B2); PIN64(B3); PIN64(B4);
            ull nz = __ballot((B0 | B1 | B2 | B3 | B4) != 0ull);
            while (nz) {
                int i = __builtin_ctzll(nz);
                nz &= nz - 1;
                if (!((rem4 >> i) & 1ull)) {
                    rem0 |= readlane64(B0, i); rem1 |= readlane64(B1, i);
                    rem2 |= readlane64(B2, i); rem3 |= readlane64(B3, i);
                    rem4 |= readlane64(B4, i);
                }
            }
        }
        if (lane == 0) {
            s_remC[0] = rem0; s_remC[1] = rem1; s_remC[2] = rem2;
            s_remC[3] = rem3; s_remC[4] = rem4;
        }
    }
    __syncthreads();

    // ---- output: thread r writes row r (coalesced 24B/thread). Inactive
    // (zero-area) rows are never suppressed -> kept; active rows look up
    // their compacted suppressed bit. ----
    {
        const int r = tid;
        if (r < TOPK) {
            float x1 = 0.f, y1 = 0.f, x2 = 0.f, y2 = 0.f, vv = 0.f, cc = 0.f;
            if (r < numSel) {
                bool sup = false;
                if (sAr[r] > 0.0f) {
                    int p = (int)sPos[r];
                    sup = (s_remC[p >> 6] >> (p & 63)) & 1ull;
                }
                if (!sup) {
                    float4 bb = sBox[r];
                    x1 = bb.x; y1 = bb.y; x2 = bb.z; y2 = bb.w;
                    vv = sVal[r]; cc = (float)c;
                }
            }
            float* outp = out + ((size_t)b * NC + c) * (TOPK * 6);
            float* row = outp + r * 6;
            *(float2*)(row)     = float2{x1, y1};
            *(float2*)(row + 2) = float2{x2, y2};
            *(float2*)(row + 4) = float2{vv, cc};
        }
    }
}

extern "C" void kernel_launch(void* const* d_in, const int* in_sizes, int n_in,
                              void* d_out, int out_size, void* d_ws, size_t ws_size,
                              hipStream_t stream) {
    const float* in = (const float*)d_in[0];
    float* out = (float*)d_out;
    (void)d_ws; (void)ws_size;   // fused kernel keeps all intermediates in LDS

    k_fused<<<NTASK, NT, 0, stream>>>(in, out);
}